// Round 11
// baseline (457.415 us; speedup 1.0000x reference)
//
#include <hip/hip_runtime.h>
#include <stdint.h>

#define SEQ 2048
#define DIN 2048
#define NH 16
#define HD 128

typedef __attribute__((ext_vector_type(8))) short bf16x8;
typedef __attribute__((ext_vector_type(4))) float f32x4;

__device__ __forceinline__ unsigned short f2bf(float f) {
    unsigned int u = __float_as_uint(f);
    u += 0x7fff + ((u >> 16) & 1);   // round-to-nearest-even
    return (unsigned short)(u >> 16);
}

__device__ __forceinline__ float bf2f(unsigned short u) {
    return __uint_as_float(((unsigned int)u) << 16);
}

__device__ __forceinline__ void gload_lds16(const void* g, void* l) {
    __builtin_amdgcn_global_load_lds(
        (const __attribute__((address_space(1))) unsigned int*)g,
        (__attribute__((address_space(3))) unsigned int*)l,
        16, 0, 0);
}

// ---------------- fused cast f32 -> bf16 for all 5 tensors ----------------
// vec4 segments: x 1048576 | wq 1048576 | wk 65536 | wv 65536 | wo 1048576
// total = 3276800 vec4 -> grid 12800 x 256 (EXACT; round-5's 3342336 bound was an OOB bug)
__global__ void cast_all(const float* __restrict__ x,  const float* __restrict__ wq,
                         const float* __restrict__ wk, const float* __restrict__ wv,
                         const float* __restrict__ wo,
                         unsigned short* __restrict__ xb, unsigned short* __restrict__ wqkv,
                         unsigned short* __restrict__ wob) {
    int i = blockIdx.x * blockDim.x + threadIdx.x;   // vec4 index
    if (i >= 3276800) return;
    const float* src; unsigned short* dst; int off;
    if (i < 1048576)      { src = x;  dst = xb;             off = i; }
    else if (i < 2097152) { src = wq; dst = wqkv;           off = i - 1048576; }
    else if (i < 2162688) { src = wk; dst = wqkv + 4194304; off = i - 2097152; }
    else if (i < 2228224) { src = wv; dst = wqkv + 4456448; off = i - 2162688; }
    else                  { src = wo; dst = wob;            off = i - 2228224; }
    float4 v = *reinterpret_cast<const float4*>(src + (size_t)off * 4);
    ushort4 o;
    o.x = f2bf(v.x); o.y = f2bf(v.y); o.z = f2bf(v.z); o.w = f2bf(v.w);
    *reinterpret_cast<ushort4*>(dst + (size_t)off * 4) = o;
}

// ------- merged QKV projection (8 waves): A[2048][2048] * W[2304][2048]^T -------
// col-tile bx<17 -> qkpre[row][col] (stride 2176, bf16); bx==17 -> vtb[col-2176][row] (V^T)
__launch_bounds__(512)
__global__ void gemm_qkv(const unsigned short* __restrict__ A,
                         const unsigned short* __restrict__ B,
                         unsigned short* __restrict__ qkpre,
                         unsigned short* __restrict__ vtb) {
    __shared__ __align__(16) unsigned short As[128 * 32];
    __shared__ __align__(16) unsigned short Bs[128 * 32];
    const int t = threadIdx.x;
    const int l = t & 63;
    const int w = t >> 6;
    const int wr = w >> 1, wc = w & 1;
    const int row0 = blockIdx.y * 128, col0 = blockIdx.x * 128;
    const int lr = l & 15, lk = (l >> 4) * 8;
    const int K = DIN;

    f32x4 acc[2][4] = {};
    const unsigned short* Ag = A + (size_t)(row0 + t / 4) * K + (t % 4) * 8;
    const unsigned short* Bg = B + (size_t)(col0 + t / 4) * K + (t % 4) * 8;

    for (int k0 = 0; k0 < K; k0 += 32) {
        gload_lds16(Ag + k0, &As[t * 8]);
        gload_lds16(Bg + k0, &Bs[t * 8]);
        __syncthreads();
        bf16x8 af[2], bfr[4];
#pragma unroll
        for (int m = 0; m < 2; ++m)
            af[m] = *reinterpret_cast<const bf16x8*>(&As[(wr * 32 + m * 16 + lr) * 32 + lk]);
#pragma unroll
        for (int n = 0; n < 4; ++n)
            bfr[n] = *reinterpret_cast<const bf16x8*>(&Bs[(wc * 64 + n * 16 + lr) * 32 + lk]);
#pragma unroll
        for (int m = 0; m < 2; ++m)
#pragma unroll
            for (int n = 0; n < 4; ++n)
                acc[m][n] = __builtin_amdgcn_mfma_f32_16x16x32_bf16(af[m], bfr[n], acc[m][n], 0, 0, 0);
        __syncthreads();
    }

    const bool isV = (blockIdx.x == 17);
#pragma unroll
    for (int m = 0; m < 2; ++m) {
        int row_b = row0 + wr * 32 + m * 16 + (l >> 4) * 4;
#pragma unroll
        for (int n = 0; n < 4; ++n) {
            int col = col0 + wc * 64 + n * 16 + lr;
#pragma unroll
            for (int jr = 0; jr < 4; ++jr) {
                int row = row_b + jr;
                if (isV)
                    vtb[(size_t)(col - 2176) * SEQ + row] = f2bf(acc[m][n][jr]);
                else
                    qkpre[(size_t)row * 2176 + col] = f2bf(acc[m][n][jr]);
            }
        }
    }
}

// ------- GEMM (8 waves): C[M][N] = A[M][K] * B[N][K]^T, f32 out -------
__launch_bounds__(512)
__global__ void gemm_bt8(const unsigned short* __restrict__ A,
                         const unsigned short* __restrict__ B,
                         float* __restrict__ C, int M, int N, int K) {
    __shared__ __align__(16) unsigned short As[128 * 32];
    __shared__ __align__(16) unsigned short Bs[128 * 32];
    const int t = threadIdx.x;
    const int l = t & 63;
    const int w = t >> 6;
    const int wr = w >> 1, wc = w & 1;
    const int row0 = blockIdx.y * 128, col0 = blockIdx.x * 128;
    const int lr = l & 15, lk = (l >> 4) * 8;

    f32x4 acc[2][4] = {};
    const unsigned short* Ag = A + (size_t)(row0 + t / 4) * K + (t % 4) * 8;
    const unsigned short* Bg = B + (size_t)(col0 + t / 4) * K + (t % 4) * 8;

    for (int k0 = 0; k0 < K; k0 += 32) {
        gload_lds16(Ag + k0, &As[t * 8]);
        gload_lds16(Bg + k0, &Bs[t * 8]);
        __syncthreads();
        bf16x8 af[2], bfr[4];
#pragma unroll
        for (int m = 0; m < 2; ++m)
            af[m] = *reinterpret_cast<const bf16x8*>(&As[(wr * 32 + m * 16 + lr) * 32 + lk]);
#pragma unroll
        for (int n = 0; n < 4; ++n)
            bfr[n] = *reinterpret_cast<const bf16x8*>(&Bs[(wc * 64 + n * 16 + lr) * 32 + lk]);
#pragma unroll
        for (int m = 0; m < 2; ++m)
#pragma unroll
            for (int n = 0; n < 4; ++n)
                acc[m][n] = __builtin_amdgcn_mfma_f32_16x16x32_bf16(af[m], bfr[n], acc[m][n], 0, 0, 0);
        __syncthreads();
    }

#pragma unroll
    for (int m = 0; m < 2; ++m) {
        int row_b = row0 + wr * 32 + m * 16 + (l >> 4) * 4;
#pragma unroll
        for (int n = 0; n < 4; ++n) {
            int col = col0 + wc * 64 + n * 16 + lr;
#pragma unroll
            for (int jr = 0; jr < 4; ++jr)
                C[(size_t)(row_b + jr) * N + col] = acc[m][n][jr];
        }
    }
}

// ---------------- fused RMSNorm + RoPE for Q and K (bf16 in/out) ----------------
__global__ void norm_rope_all(const unsigned short* __restrict__ qk,
                              unsigned short* __restrict__ qout,
                              unsigned short* __restrict__ kout,
                              const float* __restrict__ sin_t, const float* __restrict__ cos_t,
                              const float* __restrict__ q_scale, const float* __restrict__ q_shift,
                              const float* __restrict__ k_scale, const float* __restrict__ k_shift) {
    int w = threadIdx.x >> 6, lane = threadIdx.x & 63;
    int vec = blockIdx.x * 4 + w;
    if (vec >= SEQ * NH + SEQ) return;
    const unsigned short* base;
    unsigned short* outp;
    const float *scale, *shift;
    int s;
    if (vec < SEQ * NH) {
        s = vec >> 4;
        int hh = vec & 15;
        base = qk + (size_t)s * 2176 + hh * HD;
        outp = qout + (size_t)vec * HD;
        scale = q_scale; shift = q_shift;
    } else {
        s = vec - SEQ * NH;
        base = qk + (size_t)s * 2176 + NH * HD;
        outp = kout + (size_t)s * HD;
        scale = k_scale; shift = k_shift;
    }
    float x1 = bf2f(base[lane]), x2 = bf2f(base[lane + 64]);
    float ss = x1 * x1 + x2 * x2;
#pragma unroll
    for (int off = 1; off < 64; off <<= 1) ss += __shfl_xor(ss, off, 64);
    float rinv = rsqrtf(ss * (1.0f / 128.0f) + 1e-6f);
    float xn1 = x1 * rinv * (1.0f + scale[lane]) + shift[lane];
    float xn2 = x2 * rinv * (1.0f + scale[lane + 64]) + shift[lane + 64];
    float c1 = cos_t[s * HD + lane], s1 = sin_t[s * HD + lane];
    float c2 = cos_t[s * HD + lane + 64], s2 = sin_t[s * HD + lane + 64];
    outp[lane]      = f2bf(xn1 * c1 - xn2 * s1);
    outp[lane + 64] = f2bf(xn2 * c2 + xn1 * s2);
}

// ---------------- flash causal attention v5: 56KB LDS, plain-barrier pipeline ----------------
// 512 blocks; bx<256 -> qt=31-(bx>>4) (heavy, dispatched first), else qt=(bx-256)>>4; h=bx&15.
// 2 blocks/CU co-resident (56KB x 2 = 112KB LDS). All sync via __syncthreads (compiler-managed).
__launch_bounds__(256, 2)
__global__ void flash_attn5(const unsigned short* __restrict__ Q,
                            const unsigned short* __restrict__ Kb,
                            const unsigned short* __restrict__ Vtg,  // [HD][SEQ]
                            unsigned short* __restrict__ O) {
    __shared__ __align__(16) unsigned short Ks[2][64 * 128];  // 32 KB, double-buffered
    __shared__ __align__(16) unsigned short Vs[128 * 64];     // 16 KB, single
    __shared__ __align__(16) unsigned short Pl[4][16 * 64];   // 8 KB
    const int t = threadIdx.x, l = t & 63, w = t >> 6;
    const int bx = blockIdx.x;
    const int qt = (bx < 256) ? (31 - (bx >> 4)) : ((bx - 256) >> 4);
    const int h = bx & 15;
    const int lr = l & 15, g = l >> 4, lk = g * 8;
    const float sc = 0.08838834764831845f; // 1/sqrt(128)

    auto stageK = [&](int buf, int k0) {
#pragma unroll
        for (int i = 0; i < 4; ++i) {
            int c = w * 256 + i * 64 + l;
            int kr = c >> 4, kc = c & 15;
            gload_lds16(Kb + (size_t)(k0 + kr) * HD + ((kc ^ (kr & 7)) * 8),
                        &Ks[buf][c * 8]);
        }
    };
    auto stageV = [&](int k0) {
#pragma unroll
        for (int i = 0; i < 4; ++i) {
            int c = w * 256 + i * 64 + l;
            int vd = c >> 3, vc = c & 7;
            gload_lds16(Vtg + (size_t)vd * SEQ + k0 + ((vc ^ (vd & 7)) * 8),
                        &Vs[c * 8]);
        }
    };

    const int q0 = qt * 64;
    bf16x8 qf[4];
    const unsigned short* qbase = Q + (size_t)(q0 + w * 16 + lr) * (NH * HD) + h * HD + lk;
#pragma unroll
    for (int kf = 0; kf < 4; ++kf)
        qf[kf] = *reinterpret_cast<const bf16x8*>(qbase + kf * 32);

    f32x4 acc[8] = {};
    float mrow[4] = {-1e30f, -1e30f, -1e30f, -1e30f};
    float lrow[4] = {0.f, 0.f, 0.f, 0.f};
    const int nt = qt + 1;
    int buf = 0;
    stageK(0, 0);
    __syncthreads();

    for (int kt = 0; kt < nt; ++kt) {
        const bool pf = (kt + 1 < nt);
        // issue V[kt] and K[kt+1] loads early; their latency is covered by QK^T + softmax
        stageV(kt * 64);
        if (pf) stageK(buf ^ 1, (kt + 1) * 64);

        // S = Q K^T (16 q-rows x 64 keys per wave)
        f32x4 s4[4];
#pragma unroll
        for (int nf = 0; nf < 4; ++nf) {
            int row = nf * 16 + lr;
            f32x4 a = {};
#pragma unroll
            for (int kf = 0; kf < 4; ++kf) {
                bf16x8 kfrag = *reinterpret_cast<const bf16x8*>(
                    &Ks[buf][row * 128 + ((kf * 32 + lk) ^ ((row & 7) << 3))]);
                a = __builtin_amdgcn_mfma_f32_16x16x32_bf16(qf[kf], kfrag, a, 0, 0, 0);
            }
            s4[nf] = a;
        }

        // scale + (diagonal-only) mask
        float sv[4][4];
        const bool diag = (kt == qt);
#pragma unroll
        for (int jr = 0; jr < 4; ++jr)
#pragma unroll
            for (int nf = 0; nf < 4; ++nf) {
                float x = s4[nf][jr] * sc;
                if (diag && (nf * 16 + lr > w * 16 + g * 4 + jr)) x = -1e30f;
                sv[jr][nf] = x;
            }

        float mx[4];
#pragma unroll
        for (int jr = 0; jr < 4; ++jr) {
            float m2 = fmaxf(fmaxf(sv[jr][0], sv[jr][1]), fmaxf(sv[jr][2], sv[jr][3]));
            m2 = fmaxf(m2, __shfl_xor(m2, 1, 64));
            m2 = fmaxf(m2, __shfl_xor(m2, 2, 64));
            m2 = fmaxf(m2, __shfl_xor(m2, 4, 64));
            m2 = fmaxf(m2, __shfl_xor(m2, 8, 64));
            mx[jr] = m2;
        }
        int pred = (mx[0] - mrow[0] <= 8.f) && (mx[1] - mrow[1] <= 8.f) &&
                   (mx[2] - mrow[2] <= 8.f) && (mx[3] - mrow[3] <= 8.f);
        const bool skip = __all(pred);   // defer-max (T13)

#pragma unroll
        for (int jr = 0; jr < 4; ++jr) {
            float mnew = skip ? mrow[jr] : fmaxf(mrow[jr], mx[jr]);
            int row = g * 4 + jr;
            float ps = 0.f;
#pragma unroll
            for (int nf = 0; nf < 4; ++nf) {
                float p = __expf(sv[jr][nf] - mnew);
                ps += p;
                int col = nf * 16 + lr;
                Pl[w][row * 64 + (col ^ ((row & 12) << 2))] = f2bf(p);
            }
            ps += __shfl_xor(ps, 1, 64);
            ps += __shfl_xor(ps, 2, 64);
            ps += __shfl_xor(ps, 4, 64);
            ps += __shfl_xor(ps, 8, 64);
            if (!skip) {
                float corr = __expf(mrow[jr] - mnew);
                mrow[jr] = mnew;
                lrow[jr] = lrow[jr] * corr + ps;
#pragma unroll
                for (int nf = 0; nf < 8; ++nf) acc[nf][jr] *= corr;
            } else {
                lrow[jr] += ps;
            }
        }

        // V[kt] (and K[kt+1]) now resident for all threads
        __syncthreads();

        // O += P V
#pragma unroll
        for (int kf = 0; kf < 2; ++kf) {
            bf16x8 pfrag = *reinterpret_cast<const bf16x8*>(
                &Pl[w][lr * 64 + ((kf * 32 + lk) ^ ((lr & 12) << 2))]);
#pragma unroll
            for (int nf = 0; nf < 8; ++nf) {
                int d = nf * 16 + lr;
                bf16x8 vf = *reinterpret_cast<const bf16x8*>(
                    &Vs[d * 64 + ((kf * 32 + lk) ^ ((d & 7) << 3))]);
                acc[nf] = __builtin_amdgcn_mfma_f32_16x16x32_bf16(pfrag, vf, acc[nf], 0, 0, 0);
            }
        }
        __syncthreads();   // Vs/Pl safe to overwrite next iter
        buf ^= 1;
    }

#pragma unroll
    for (int jr = 0; jr < 4; ++jr) {
        float inv = 1.0f / lrow[jr];
        int row = q0 + w * 16 + g * 4 + jr;
#pragma unroll
        for (int nf = 0; nf < 8; ++nf) {
            int col = nf * 16 + lr;
            O[(size_t)row * (NH * HD) + h * HD + col] = f2bf(acc[nf][jr] * inv);
        }
    }
}

extern "C" void kernel_launch(void* const* d_in, const int* in_sizes, int n_in,
                              void* d_out, int out_size, void* d_ws, size_t ws_size,
                              hipStream_t stream) {
    const float* x      = (const float*)d_in[0];
    const float* sin_t  = (const float*)d_in[2];
    const float* cos_t  = (const float*)d_in[3];
    const float* w_q    = (const float*)d_in[4];
    const float* w_k    = (const float*)d_in[5];
    const float* w_v    = (const float*)d_in[6];
    const float* w_o    = (const float*)d_in[7];
    const float* q_scale = (const float*)d_in[8];
    const float* q_shift = (const float*)d_in[9];
    const float* k_scale = (const float*)d_in[10];
    const float* k_shift = (const float*)d_in[11];
    float* out = (float*)d_out;

    char* ws = (char*)d_ws;
    const size_t MB = 1u << 20;
    unsigned short* xb    = (unsigned short*)(ws);                          // 8 MB    x bf16 [2048][2048]
    unsigned short* wqkvb = (unsigned short*)(ws + 8 * MB);                 // 9 MB    w_q|w_k|w_v [2304][2048]
    unsigned short* wob   = (unsigned short*)(ws + 17 * MB);                // 8 MB    w_o
    unsigned short* qkpre = (unsigned short*)(ws + 25 * MB);                // 8.5 MB  pre-norm Q|K [2048][2176]
    unsigned short* vtb   = (unsigned short*)(ws + 33 * MB + 512 * 1024);   // 0.5 MB  V^T [128][2048]
    unsigned short* qb    = (unsigned short*)(ws + 34 * MB);                // 8 MB    post-rope Q
    unsigned short* kb    = (unsigned short*)(ws + 42 * MB);                // 0.5 MB  post-rope K
    unsigned short* ab    = (unsigned short*)(ws + 42 * MB + 512 * 1024);   // 8 MB    attn out
    // total ~50.5 MB

    // fused casts (1 launch, exact grid: 3276800 vec4 / 256)
    cast_all<<<12800, 256, 0, stream>>>(x, w_q, w_k, w_v, w_o, xb, wqkvb, wob);

    // merged Q|K|V projection (V written transposed)
    gemm_qkv<<<dim3(18, 16), 512, 0, stream>>>(xb, wqkvb, qkpre, vtb);

    // fused norm + rope (Q and K)
    norm_rope_all<<<(SEQ * NH + SEQ) / 4, 256, 0, stream>>>(
        qkpre, qb, kb, sin_t, cos_t, q_scale, q_shift, k_scale, k_shift);

    // attention
    flash_attn5<<<512, 256, 0, stream>>>(qb, kb, vtb, ab);

    // output projection (f32 out -> d_out)
    gemm_bt8<<<dim3(16, 16), 512, 0, stream>>>(ab, wob, out, SEQ, NH * HD, DIN);
}

// Round 12
// 342.461 us; speedup vs baseline: 1.3357x; 1.3357x over previous
//
#include <hip/hip_runtime.h>
#include <stdint.h>

#define SEQ 2048
#define DIN 2048
#define NH 16
#define HD 128

typedef __attribute__((ext_vector_type(8))) short bf16x8;
typedef __attribute__((ext_vector_type(4))) float f32x4;

__device__ __forceinline__ unsigned short f2bf(float f) {
    unsigned int u = __float_as_uint(f);
    u += 0x7fff + ((u >> 16) & 1);   // round-to-nearest-even
    return (unsigned short)(u >> 16);
}

__device__ __forceinline__ float bf2f(unsigned short u) {
    return __uint_as_float(((unsigned int)u) << 16);
}

__device__ __forceinline__ void gload_lds16(const void* g, void* l) {
    __builtin_amdgcn_global_load_lds(
        (const __attribute__((address_space(1))) unsigned int*)g,
        (__attribute__((address_space(3))) unsigned int*)l,
        16, 0, 0);
}

// ---------------- fused cast f32 -> bf16 for all 5 tensors ----------------
// vec4 segments: x 1048576 | wq 1048576 | wk 65536 | wv 65536 | wo 1048576
// total = 3276800 vec4 -> grid 12800 x 256 (EXACT)
__global__ void cast_all(const float* __restrict__ x,  const float* __restrict__ wq,
                         const float* __restrict__ wk, const float* __restrict__ wv,
                         const float* __restrict__ wo,
                         unsigned short* __restrict__ xb, unsigned short* __restrict__ wqkv,
                         unsigned short* __restrict__ wob) {
    int i = blockIdx.x * blockDim.x + threadIdx.x;   // vec4 index
    if (i >= 3276800) return;
    const float* src; unsigned short* dst; int off;
    if (i < 1048576)      { src = x;  dst = xb;             off = i; }
    else if (i < 2097152) { src = wq; dst = wqkv;           off = i - 1048576; }
    else if (i < 2162688) { src = wk; dst = wqkv + 4194304; off = i - 2097152; }
    else if (i < 2228224) { src = wv; dst = wqkv + 4456448; off = i - 2162688; }
    else                  { src = wo; dst = wob;            off = i - 2228224; }
    float4 v = *reinterpret_cast<const float4*>(src + (size_t)off * 4);
    ushort4 o;
    o.x = f2bf(v.x); o.y = f2bf(v.y); o.z = f2bf(v.z); o.w = f2bf(v.w);
    *reinterpret_cast<ushort4*>(dst + (size_t)off * 4) = o;
}

// ------- merged QKV projection (8 waves): A[2048][2048] * W[2304][2048]^T -------
// col-tile bx<17 -> qkpre[row][col] (stride 2176, bf16); bx==17 -> vtb[col-2176][row] (V^T)
__launch_bounds__(512)
__global__ void gemm_qkv(const unsigned short* __restrict__ A,
                         const unsigned short* __restrict__ B,
                         unsigned short* __restrict__ qkpre,
                         unsigned short* __restrict__ vtb) {
    __shared__ __align__(16) unsigned short As[128 * 32];
    __shared__ __align__(16) unsigned short Bs[128 * 32];
    const int t = threadIdx.x;
    const int l = t & 63;
    const int w = t >> 6;
    const int wr = w >> 1, wc = w & 1;
    const int row0 = blockIdx.y * 128, col0 = blockIdx.x * 128;
    const int lr = l & 15, lk = (l >> 4) * 8;
    const int K = DIN;

    f32x4 acc[2][4] = {};
    const unsigned short* Ag = A + (size_t)(row0 + t / 4) * K + (t % 4) * 8;
    const unsigned short* Bg = B + (size_t)(col0 + t / 4) * K + (t % 4) * 8;

    for (int k0 = 0; k0 < K; k0 += 32) {
        gload_lds16(Ag + k0, &As[t * 8]);
        gload_lds16(Bg + k0, &Bs[t * 8]);
        __syncthreads();
        bf16x8 af[2], bfr[4];
#pragma unroll
        for (int m = 0; m < 2; ++m)
            af[m] = *reinterpret_cast<const bf16x8*>(&As[(wr * 32 + m * 16 + lr) * 32 + lk]);
#pragma unroll
        for (int n = 0; n < 4; ++n)
            bfr[n] = *reinterpret_cast<const bf16x8*>(&Bs[(wc * 64 + n * 16 + lr) * 32 + lk]);
#pragma unroll
        for (int m = 0; m < 2; ++m)
#pragma unroll
            for (int n = 0; n < 4; ++n)
                acc[m][n] = __builtin_amdgcn_mfma_f32_16x16x32_bf16(af[m], bfr[n], acc[m][n], 0, 0, 0);
        __syncthreads();
    }

    const bool isV = (blockIdx.x == 17);
#pragma unroll
    for (int m = 0; m < 2; ++m) {
        int row_b = row0 + wr * 32 + m * 16 + (l >> 4) * 4;
#pragma unroll
        for (int n = 0; n < 4; ++n) {
            int col = col0 + wc * 64 + n * 16 + lr;
#pragma unroll
            for (int jr = 0; jr < 4; ++jr) {
                int row = row_b + jr;
                if (isV)
                    vtb[(size_t)(col - 2176) * SEQ + row] = f2bf(acc[m][n][jr]);
                else
                    qkpre[(size_t)row * 2176 + col] = f2bf(acc[m][n][jr]);
            }
        }
    }
}

// ------- GEMM (8 waves): C[M][N] = A[M][K] * B[N][K]^T, f32 out -------
__launch_bounds__(512)
__global__ void gemm_bt8(const unsigned short* __restrict__ A,
                         const unsigned short* __restrict__ B,
                         float* __restrict__ C, int M, int N, int K) {
    __shared__ __align__(16) unsigned short As[128 * 32];
    __shared__ __align__(16) unsigned short Bs[128 * 32];
    const int t = threadIdx.x;
    const int l = t & 63;
    const int w = t >> 6;
    const int wr = w >> 1, wc = w & 1;
    const int row0 = blockIdx.y * 128, col0 = blockIdx.x * 128;
    const int lr = l & 15, lk = (l >> 4) * 8;

    f32x4 acc[2][4] = {};
    const unsigned short* Ag = A + (size_t)(row0 + t / 4) * K + (t % 4) * 8;
    const unsigned short* Bg = B + (size_t)(col0 + t / 4) * K + (t % 4) * 8;

    for (int k0 = 0; k0 < K; k0 += 32) {
        gload_lds16(Ag + k0, &As[t * 8]);
        gload_lds16(Bg + k0, &Bs[t * 8]);
        __syncthreads();
        bf16x8 af[2], bfr[4];
#pragma unroll
        for (int m = 0; m < 2; ++m)
            af[m] = *reinterpret_cast<const bf16x8*>(&As[(wr * 32 + m * 16 + lr) * 32 + lk]);
#pragma unroll
        for (int n = 0; n < 4; ++n)
            bfr[n] = *reinterpret_cast<const bf16x8*>(&Bs[(wc * 64 + n * 16 + lr) * 32 + lk]);
#pragma unroll
        for (int m = 0; m < 2; ++m)
#pragma unroll
            for (int n = 0; n < 4; ++n)
                acc[m][n] = __builtin_amdgcn_mfma_f32_16x16x32_bf16(af[m], bfr[n], acc[m][n], 0, 0, 0);
        __syncthreads();
    }

#pragma unroll
    for (int m = 0; m < 2; ++m) {
        int row_b = row0 + wr * 32 + m * 16 + (l >> 4) * 4;
#pragma unroll
        for (int n = 0; n < 4; ++n) {
            int col = col0 + wc * 64 + n * 16 + lr;
#pragma unroll
            for (int jr = 0; jr < 4; ++jr)
                C[(size_t)(row_b + jr) * N + col] = acc[m][n][jr];
        }
    }
}

// ---------------- fused RMSNorm + RoPE for Q and K (bf16 in/out) ----------------
__global__ void norm_rope_all(const unsigned short* __restrict__ qk,
                              unsigned short* __restrict__ qout,
                              unsigned short* __restrict__ kout,
                              const float* __restrict__ sin_t, const float* __restrict__ cos_t,
                              const float* __restrict__ q_scale, const float* __restrict__ q_shift,
                              const float* __restrict__ k_scale, const float* __restrict__ k_shift) {
    int w = threadIdx.x >> 6, lane = threadIdx.x & 63;
    int vec = blockIdx.x * 4 + w;
    if (vec >= SEQ * NH + SEQ) return;
    const unsigned short* base;
    unsigned short* outp;
    const float *scale, *shift;
    int s;
    if (vec < SEQ * NH) {
        s = vec >> 4;
        int hh = vec & 15;
        base = qk + (size_t)s * 2176 + hh * HD;
        outp = qout + (size_t)vec * HD;
        scale = q_scale; shift = q_shift;
    } else {
        s = vec - SEQ * NH;
        base = qk + (size_t)s * 2176 + NH * HD;
        outp = kout + (size_t)s * HD;
        scale = k_scale; shift = k_shift;
    }
    float x1 = bf2f(base[lane]), x2 = bf2f(base[lane + 64]);
    float ss = x1 * x1 + x2 * x2;
#pragma unroll
    for (int off = 1; off < 64; off <<= 1) ss += __shfl_xor(ss, off, 64);
    float rinv = rsqrtf(ss * (1.0f / 128.0f) + 1e-6f);
    float xn1 = x1 * rinv * (1.0f + scale[lane]) + shift[lane];
    float xn2 = x2 * rinv * (1.0f + scale[lane + 64]) + shift[lane + 64];
    float c1 = cos_t[s * HD + lane], s1 = sin_t[s * HD + lane];
    float c2 = cos_t[s * HD + lane + 64], s2 = sin_t[s * HD + lane + 64];
    outp[lane]      = f2bf(xn1 * c1 - xn2 * s1);
    outp[lane + 64] = f2bf(xn2 * c2 + xn1 * s2);
}

// ---------------- flash causal attention v6: 56KB LDS, NO forced min-occupancy ----------------
// 512 blocks; bx<256 -> qt=31-(bx>>4) (heavy, dispatched first), else qt=(bx-256)>>4; h=bx&15.
// Co-residency comes from LDS (2 x 56KB <= 160KB) + natural VGPR allocation (no spill).
__launch_bounds__(256)
__global__ void flash_attn6(const unsigned short* __restrict__ Q,
                            const unsigned short* __restrict__ Kb,
                            const unsigned short* __restrict__ Vtg,  // [HD][SEQ]
                            unsigned short* __restrict__ O) {
    __shared__ __align__(16) unsigned short Ks[2][64 * 128];  // 32 KB, double-buffered
    __shared__ __align__(16) unsigned short Vs[128 * 64];     // 16 KB, single
    __shared__ __align__(16) unsigned short Pl[4][16 * 64];   // 8 KB
    const int t = threadIdx.x, l = t & 63, w = t >> 6;
    const int bx = blockIdx.x;
    const int qt = (bx < 256) ? (31 - (bx >> 4)) : ((bx - 256) >> 4);
    const int h = bx & 15;
    const int lr = l & 15, g = l >> 4, lk = g * 8;
    const float sc = 0.08838834764831845f; // 1/sqrt(128)

    auto stageK = [&](int buf, int k0) {
#pragma unroll
        for (int i = 0; i < 4; ++i) {
            int c = w * 256 + i * 64 + l;
            int kr = c >> 4, kc = c & 15;
            gload_lds16(Kb + (size_t)(k0 + kr) * HD + ((kc ^ (kr & 7)) * 8),
                        &Ks[buf][c * 8]);
        }
    };
    auto stageV = [&](int k0) {
#pragma unroll
        for (int i = 0; i < 4; ++i) {
            int c = w * 256 + i * 64 + l;
            int vd = c >> 3, vc = c & 7;
            gload_lds16(Vtg + (size_t)vd * SEQ + k0 + ((vc ^ (vd & 7)) * 8),
                        &Vs[c * 8]);
        }
    };

    const int q0 = qt * 64;
    bf16x8 qf[4];
    const unsigned short* qbase = Q + (size_t)(q0 + w * 16 + lr) * (NH * HD) + h * HD + lk;
#pragma unroll
    for (int kf = 0; kf < 4; ++kf)
        qf[kf] = *reinterpret_cast<const bf16x8*>(qbase + kf * 32);

    f32x4 acc[8] = {};
    float mrow[4] = {-1e30f, -1e30f, -1e30f, -1e30f};
    float lrow[4] = {0.f, 0.f, 0.f, 0.f};
    const int nt = qt + 1;
    int buf = 0;
    stageK(0, 0);
    __syncthreads();

    for (int kt = 0; kt < nt; ++kt) {
        const bool pf = (kt + 1 < nt);
        // issue V[kt] and K[kt+1] loads early; latency covered by QK^T + softmax
        stageV(kt * 64);
        if (pf) stageK(buf ^ 1, (kt + 1) * 64);

        // S = Q K^T (16 q-rows x 64 keys per wave); fold scale+mask in place
        f32x4 s4[4];
        const bool diag = (kt == qt);
#pragma unroll
        for (int nf = 0; nf < 4; ++nf) {
            int row = nf * 16 + lr;
            f32x4 a = {};
#pragma unroll
            for (int kf = 0; kf < 4; ++kf) {
                bf16x8 kfrag = *reinterpret_cast<const bf16x8*>(
                    &Ks[buf][row * 128 + ((kf * 32 + lk) ^ ((row & 7) << 3))]);
                a = __builtin_amdgcn_mfma_f32_16x16x32_bf16(qf[kf], kfrag, a, 0, 0, 0);
            }
#pragma unroll
            for (int jr = 0; jr < 4; ++jr) {
                float x = a[jr] * sc;
                if (diag && (nf * 16 + lr > w * 16 + g * 4 + jr)) x = -1e30f;
                a[jr] = x;
            }
            s4[nf] = a;
        }

        float mx[4];
#pragma unroll
        for (int jr = 0; jr < 4; ++jr) {
            float m2 = fmaxf(fmaxf(s4[0][jr], s4[1][jr]), fmaxf(s4[2][jr], s4[3][jr]));
            m2 = fmaxf(m2, __shfl_xor(m2, 1, 64));
            m2 = fmaxf(m2, __shfl_xor(m2, 2, 64));
            m2 = fmaxf(m2, __shfl_xor(m2, 4, 64));
            m2 = fmaxf(m2, __shfl_xor(m2, 8, 64));
            mx[jr] = m2;
        }
        int pred = (mx[0] - mrow[0] <= 8.f) && (mx[1] - mrow[1] <= 8.f) &&
                   (mx[2] - mrow[2] <= 8.f) && (mx[3] - mrow[3] <= 8.f);
        const bool skip = __all(pred);   // defer-max (T13)

#pragma unroll
        for (int jr = 0; jr < 4; ++jr) {
            float mnew = skip ? mrow[jr] : fmaxf(mrow[jr], mx[jr]);
            int row = g * 4 + jr;
            float ps = 0.f;
#pragma unroll
            for (int nf = 0; nf < 4; ++nf) {
                float p = __expf(s4[nf][jr] - mnew);
                ps += p;
                int col = nf * 16 + lr;
                Pl[w][row * 64 + (col ^ ((row & 12) << 2))] = f2bf(p);
            }
            ps += __shfl_xor(ps, 1, 64);
            ps += __shfl_xor(ps, 2, 64);
            ps += __shfl_xor(ps, 4, 64);
            ps += __shfl_xor(ps, 8, 64);
            if (!skip) {
                float corr = __expf(mrow[jr] - mnew);
                mrow[jr] = mnew;
                lrow[jr] = lrow[jr] * corr + ps;
#pragma unroll
                for (int nf = 0; nf < 8; ++nf) acc[nf][jr] *= corr;
            } else {
                lrow[jr] += ps;
            }
        }

        // V[kt] (and K[kt+1]) now resident for all threads
        __syncthreads();

        // O += P V
#pragma unroll
        for (int kf = 0; kf < 2; ++kf) {
            bf16x8 pfrag = *reinterpret_cast<const bf16x8*>(
                &Pl[w][lr * 64 + ((kf * 32 + lk) ^ ((lr & 12) << 2))]);
#pragma unroll
            for (int nf = 0; nf < 8; ++nf) {
                int d = nf * 16 + lr;
                bf16x8 vf = *reinterpret_cast<const bf16x8*>(
                    &Vs[d * 64 + ((kf * 32 + lk) ^ ((d & 7) << 3))]);
                acc[nf] = __builtin_amdgcn_mfma_f32_16x16x32_bf16(pfrag, vf, acc[nf], 0, 0, 0);
            }
        }
        __syncthreads();   // Vs/Pl safe to overwrite next iter
        buf ^= 1;
    }

#pragma unroll
    for (int jr = 0; jr < 4; ++jr) {
        float inv = 1.0f / lrow[jr];
        int row = q0 + w * 16 + g * 4 + jr;
#pragma unroll
        for (int nf = 0; nf < 8; ++nf) {
            int col = nf * 16 + lr;
            O[(size_t)row * (NH * HD) + h * HD + col] = f2bf(acc[nf][jr] * inv);
        }
    }
}

extern "C" void kernel_launch(void* const* d_in, const int* in_sizes, int n_in,
                              void* d_out, int out_size, void* d_ws, size_t ws_size,
                              hipStream_t stream) {
    const float* x      = (const float*)d_in[0];
    const float* sin_t  = (const float*)d_in[2];
    const float* cos_t  = (const float*)d_in[3];
    const float* w_q    = (const float*)d_in[4];
    const float* w_k    = (const float*)d_in[5];
    const float* w_v    = (const float*)d_in[6];
    const float* w_o    = (const float*)d_in[7];
    const float* q_scale = (const float*)d_in[8];
    const float* q_shift = (const float*)d_in[9];
    const float* k_scale = (const float*)d_in[10];
    const float* k_shift = (const float*)d_in[11];
    float* out = (float*)d_out;

    char* ws = (char*)d_ws;
    const size_t MB = 1u << 20;
    unsigned short* xb    = (unsigned short*)(ws);                          // 8 MB    x bf16 [2048][2048]
    unsigned short* wqkvb = (unsigned short*)(ws + 8 * MB);                 // 9 MB    w_q|w_k|w_v [2304][2048]
    unsigned short* wob   = (unsigned short*)(ws + 17 * MB);                // 8 MB    w_o
    unsigned short* qkpre = (unsigned short*)(ws + 25 * MB);                // 8.5 MB  pre-norm Q|K [2048][2176]
    unsigned short* vtb   = (unsigned short*)(ws + 33 * MB + 512 * 1024);   // 0.5 MB  V^T [128][2048]
    unsigned short* qb    = (unsigned short*)(ws + 34 * MB);                // 8 MB    post-rope Q
    unsigned short* kb    = (unsigned short*)(ws + 42 * MB);                // 0.5 MB  post-rope K
    unsigned short* ab    = (unsigned short*)(ws + 42 * MB + 512 * 1024);   // 8 MB    attn out
    // total ~50.5 MB

    // fused casts (1 launch, exact grid)
    cast_all<<<12800, 256, 0, stream>>>(x, w_q, w_k, w_v, w_o, xb, wqkvb, wob);

    // merged Q|K|V projection (V written transposed)
    gemm_qkv<<<dim3(18, 16), 512, 0, stream>>>(xb, wqkvb, qkpre, vtb);

    // fused norm + rope (Q and K)
    norm_rope_all<<<(SEQ * NH + SEQ) / 4, 256, 0, stream>>>(
        qkpre, qb, kb, sin_t, cos_t, q_scale, q_shift, k_scale, k_shift);

    // attention
    flash_attn6<<<512, 256, 0, stream>>>(qb, kb, vtb, ab);

    // output projection (f32 out -> d_out)
    gemm_bt8<<<dim3(16, 16), 512, 0, stream>>>(ab, wob, out, SEQ, NH * HD, DIN);
}